// Round 2
// baseline (1128.049 us; speedup 1.0000x reference)
//
#include <hip/hip_runtime.h>

typedef __attribute__((ext_vector_type(4))) float f32x4;
typedef __attribute__((ext_vector_type(8))) short short8;
typedef __attribute__((ext_vector_type(8))) __bf16 bf16x8;
typedef __attribute__((ext_vector_type(4))) unsigned int u32x4;
typedef __attribute__((ext_vector_type(4))) unsigned short u16x4;
typedef unsigned short u16;
typedef unsigned int u32;

#define NB 2
#define S_LEN 4096
#define NHD 8
#define HID 512

__device__ __forceinline__ u16 f2bf(float f) {
  u32 u = __builtin_bit_cast(u32, f);
  u += 0x7fffu + ((u >> 16) & 1u);   // round-to-nearest-even
  return (u16)(u >> 16);
}

// MFMA wrapper hedged over the two plausible builtin signatures (V8s vs V8y).
template <typename V>
static __device__ __forceinline__ auto mfma_imp(V a, V b, f32x4 c, int)
    -> decltype(__builtin_amdgcn_mfma_f32_16x16x32_bf16(a, b, c, 0, 0, 0)) {
  return __builtin_amdgcn_mfma_f32_16x16x32_bf16(a, b, c, 0, 0, 0);
}
template <typename V>
static __device__ __forceinline__ f32x4 mfma_imp(V a, V b, f32x4 c, long) {
  return __builtin_amdgcn_mfma_f32_16x16x32_bf16(
      __builtin_bit_cast(bf16x8, a), __builtin_bit_cast(bf16x8, b), c, 0, 0, 0);
}
static __device__ __forceinline__ f32x4 mfma_bf16(short8 a, short8 b, f32x4 c) {
  return mfma_imp(a, b, c, 0);
}

// ---------------------------------------------------------------------------
// Projection GEMM: C[i][j] = sum_k X[i][k] * W[j][k] + bias[j], scaled, ->bf16
// out layout: transposeOut==0 : [(b*8+h)][s][64]   (Q, K)
//             transposeOut==1 : [(b*8+h)][64][s]   (V^T, so PV B-operand is contiguous)
// ---------------------------------------------------------------------------
__global__ __launch_bounds__(256, 2) void proj_kernel(
    const float* __restrict__ X, const float* __restrict__ W,
    const float* __restrict__ bias, u16* __restrict__ out,
    const int transposeOut, const float scale)
{
  __shared__ u16 Al[128 * 64];
  __shared__ u16 Bl[128 * 64];
  const int tid = threadIdx.x;
  const int lane = tid & 63;
  const int wid = tid >> 6;
  const int wr = (wid >> 1) << 6;
  const int wc = (wid & 1) << 6;
  const int bm = blockIdx.x << 7;
  const int bn = blockIdx.y << 7;

  f32x4 acc[4][4] = {};

#pragma unroll 1
  for (int k0 = 0; k0 < HID; k0 += 64) {
    __syncthreads();
#pragma unroll
    for (int i = 0; i < 4; ++i) {
      const int idx = i * 256 + tid;
      const int row = idx >> 3;     // 8 chunks of 8 elems per 64-wide row
      const int c = idx & 7;
      const int off = (row * 128 + c * 16) ^ ((row & 7) << 4);
      const float* ga = X + (size_t)(bm + row) * HID + k0 + c * 8;
      f32x4 a0 = *(const f32x4*)ga;
      f32x4 a1 = *(const f32x4*)(ga + 4);
      short8 pa;
      pa[0] = (short)f2bf(a0[0]); pa[1] = (short)f2bf(a0[1]);
      pa[2] = (short)f2bf(a0[2]); pa[3] = (short)f2bf(a0[3]);
      pa[4] = (short)f2bf(a1[0]); pa[5] = (short)f2bf(a1[1]);
      pa[6] = (short)f2bf(a1[2]); pa[7] = (short)f2bf(a1[3]);
      *(short8*)((char*)Al + off) = pa;
      const float* gb = W + (size_t)(bn + row) * HID + k0 + c * 8;
      f32x4 b0 = *(const f32x4*)gb;
      f32x4 b1 = *(const f32x4*)(gb + 4);
      short8 pb;
      pb[0] = (short)f2bf(b0[0]); pb[1] = (short)f2bf(b0[1]);
      pb[2] = (short)f2bf(b0[2]); pb[3] = (short)f2bf(b0[3]);
      pb[4] = (short)f2bf(b1[0]); pb[5] = (short)f2bf(b1[1]);
      pb[6] = (short)f2bf(b1[2]); pb[7] = (short)f2bf(b1[3]);
      *(short8*)((char*)Bl + off) = pb;
    }
    __syncthreads();
#pragma unroll
    for (int ks = 0; ks < 2; ++ks) {
      const int koffb = (ks * 32 + ((lane >> 4) << 3)) * 2;
      short8 af[4], bfr[4];
#pragma unroll
      for (int m = 0; m < 4; ++m) {
        const int row = wr + m * 16 + (lane & 15);
        af[m] = *(const short8*)((const char*)Al + ((row * 128 + koffb) ^ ((row & 7) << 4)));
      }
#pragma unroll
      for (int n = 0; n < 4; ++n) {
        const int row = wc + n * 16 + (lane & 15);
        bfr[n] = *(const short8*)((const char*)Bl + ((row * 128 + koffb) ^ ((row & 7) << 4)));
      }
#pragma unroll
      for (int m = 0; m < 4; ++m)
#pragma unroll
        for (int n = 0; n < 4; ++n)
          acc[m][n] = mfma_bf16(af[m], bfr[n], acc[m][n]);
    }
  }

#pragma unroll
  for (int n = 0; n < 4; ++n) {
    const int j = bn + wc + n * 16 + (lane & 15);
    const float bj = bias[j];
    const int h = j >> 6, d = j & 63;
#pragma unroll
    for (int m = 0; m < 4; ++m) {
      const int rbase = bm + wr + m * 16 + ((lane >> 4) << 2);
      const int b = rbase >> 12;
      const int s = rbase & (S_LEN - 1);
      if (!transposeOut) {
#pragma unroll
        for (int i = 0; i < 4; ++i) {
          const float v = (acc[m][n][i] + bj) * scale;
          out[(((size_t)(b * NHD + h) * S_LEN + (s + i)) << 6) + d] = f2bf(v);
        }
      } else {
        u16x4 pk;
#pragma unroll
        for (int i = 0; i < 4; ++i) pk[i] = f2bf((acc[m][n][i] + bj) * scale);
        *(u16x4*)(out + (((size_t)(b * NHD + h) * 64 + d) << 12) + s) = pk;
      }
    }
  }
}

// ---------------------------------------------------------------------------
// Fused attention, barrier-free, latency-optimized.
// Round-1 change: q-tile 128 -> 64 rows (grid 1024 = 4 blocks/CU = 16
// waves/CU, double the latency hiding) and explicit cross-kt register
// prefetch of the K fragments (kf[16]): next tile's loads are issued right
// after each fragment's last MFMA use, giving each load a near-full-body
// completion window instead of load->use back-to-back.
// One WG per (b*8+h, 64-row q-tile); 4 waves x 16 q-rows.
// K/V/Q fragments direct from global (L2/L3-resident; XCD swizzle gives each
// XCD 2 heads = 3 MB working set in its 4 MB L2).
// Swapped QK^T: S^T = K·Q^T so C-frag holds 4 consecutive KEYS per lane.
// Pass A: softmax denominators. Pass B: recompute S, write normalized W
// (fp32, nontemporal), accumulate O = P·V via wave-private LDS P.
// ---------------------------------------------------------------------------
__global__ __launch_bounds__(256, 4) void attn_kernel(
    const u16* __restrict__ Qp, const u16* __restrict__ Kp,
    const u16* __restrict__ Vt, const unsigned char* __restrict__ mask,
    float* __restrict__ outO, float* __restrict__ outW)
{
  __shared__ u16 Pl[4][16 * 128];   // per-wave normalized P (bf16, swizzled)
  __shared__ u32 anyMaskSh;

  const int tid = threadIdx.x;
  const int lane = tid & 63;
  const int wid = tid >> 6;
  const int lr = lane & 15;         // row within 16
  const int lg = lane >> 4;         // lane group 0..3

  // XCD-bijective swizzle: 1024 blocks, 8 XCDs, 128-block chunks = 2 heads
  // (K+V+Q = 3 MB fits the 4 MB per-XCD L2).
  const int bid = blockIdx.x;
  const int swz = (bid & 7) * 128 + (bid >> 3);
  const int bh = swz >> 6;          // b*8 + h
  const int q0 = (swz & 63) << 6;   // 64-row q tile
  const int b = bh >> 3;
  const int h = bh & 7;

  if (tid == 0) anyMaskSh = 0u;
  __syncthreads();
  {
    u32x4 mv = *(const u32x4*)(mask + (size_t)b * S_LEN + tid * 16);
    if (mv[0] | mv[1] | mv[2] | mv[3]) atomicOr(&anyMaskSh, 1u);
  }
  __syncthreads();
  const bool anyMask = (anyMaskSh != 0u);

  // Q fragments (MFMA B operand) straight from global — constant all kernel
  const int qrow = q0 + (wid << 4) + lr;
  short8 bq[2];
#pragma unroll
  for (int ks = 0; ks < 2; ++ks)
    bq[ks] = *(const short8*)(
        Qp + (((size_t)bh * S_LEN + qrow) << 6) + ks * 32 + lg * 8);

  // per-lane K fragment base: row (lane&15) of the head, elem offset lg*8
  const u16* kbase = Kp + (((size_t)bh * S_LEN + lr) << 6) + lg * 8;
  const unsigned char* mbase = mask + (size_t)b * S_LEN + (lg << 2);

  short8 kf[16];
#pragma unroll
  for (int rb = 0; rb < 8; ++rb) {
    kf[2 * rb]     = *(const short8*)(kbase + (rb << 10));
    kf[2 * rb + 1] = *(const short8*)(kbase + (rb << 10) + 32);
  }

  // ---------------- pass A: softmax denominators ----------------
  float lsum = 0.f;
#pragma unroll 1
  for (int kt = 0; kt < 32; ++kt) {
    const u16* kpn = kbase + ((size_t)(kt < 31 ? kt + 1 : 31) << 13);
#pragma unroll
    for (int rb = 0; rb < 8; ++rb) {
      f32x4 sv = {};
      sv = mfma_bf16(kf[2 * rb], bq[0], sv);
      sv = mfma_bf16(kf[2 * rb + 1], bq[1], sv);
      // prefetch next tile's fragments (issued before this iter's consumers
      // of younger vmem ops -> near-full-body latency window)
      kf[2 * rb]     = *(const short8*)(kpn + (rb << 10));
      kf[2 * rb + 1] = *(const short8*)(kpn + (rb << 10) + 32);
      u32 mw = 0u;
      if (anyMask) mw = *(const u32*)(mbase + (kt << 7) + (rb << 4));
      float p0 = __expf(sv[0]);
      float p1 = __expf(sv[1]);
      float p2 = __expf(sv[2]);
      float p3 = __expf(sv[3]);
      if (mw) {
        if (mw & 0x000000FFu) p0 = 0.f;
        if (mw & 0x0000FF00u) p1 = 0.f;
        if (mw & 0x00FF0000u) p2 = 0.f;
        if (mw & 0xFF000000u) p3 = 0.f;
      }
      lsum += (p0 + p1) + (p2 + p3);
    }
  }
  float inv;
  {
    float t = lsum;
    t += __shfl_xor(t, 16);
    t += __shfl_xor(t, 32);
    inv = 1.0f / t;
  }

  // ---------------- pass B: weights out + O = P·V ----------------
  // re-preload kt=0 (kf currently holds tile 31)
#pragma unroll
  for (int rb = 0; rb < 8; ++rb) {
    kf[2 * rb]     = *(const short8*)(kbase + (rb << 10));
    kf[2 * rb + 1] = *(const short8*)(kbase + (rb << 10) + 32);
  }
  float* wrow = outW + (((size_t)bh * S_LEN + qrow) << 12) + (lg << 2);
  const u16* vrow = Vt + (((size_t)bh * 64 + lr) << 12) + lg * 8;

  f32x4 oacc[4] = {};
#pragma unroll 1
  for (int kt = 0; kt < 32; ++kt) {
    const u16* kpn = kbase + ((size_t)(kt < 31 ? kt + 1 : 31) << 13);
#pragma unroll
    for (int rb = 0; rb < 8; ++rb) {
      f32x4 sv = {};
      sv = mfma_bf16(kf[2 * rb], bq[0], sv);
      sv = mfma_bf16(kf[2 * rb + 1], bq[1], sv);
      kf[2 * rb]     = *(const short8*)(kpn + (rb << 10));
      kf[2 * rb + 1] = *(const short8*)(kpn + (rb << 10) + 32);
      u32 mw = 0u;
      if (anyMask) mw = *(const u32*)(mbase + (kt << 7) + (rb << 4));
      float p0 = __expf(sv[0]) * inv;
      float p1 = __expf(sv[1]) * inv;
      float p2 = __expf(sv[2]) * inv;
      float p3 = __expf(sv[3]) * inv;
      if (mw) {
        if (mw & 0x000000FFu) p0 = 0.f;
        if (mw & 0x0000FF00u) p1 = 0.f;
        if (mw & 0x00FF0000u) p2 = 0.f;
        if (mw & 0xFF000000u) p3 = 0.f;
      }
      f32x4 wv; wv[0] = p0; wv[1] = p1; wv[2] = p2; wv[3] = p3;
      __builtin_nontemporal_store(wv, (f32x4*)(wrow + (kt << 7) + (rb << 4)));
      u16x4 pk;
      pk[0] = f2bf(p0); pk[1] = f2bf(p1); pk[2] = f2bf(p2); pk[3] = f2bf(p3);
      *(u16x4*)((char*)Pl[wid] +
          ((lr * 256 + (rb << 5) + (lg << 3)) ^ ((lr & 7) << 4))) = pk;
    }
    // PV: P is wave-private (same-wave RAW on LDS — no barrier needed);
    // V^T fragments straight from global (L2-hot).
#pragma unroll
    for (int kk = 0; kk < 4; ++kk) {
      short8 ap = *(const short8*)((const char*)Pl[wid] +
          ((lr * 256 + (kk << 6) + (lg << 4)) ^ ((lr & 7) << 4)));
#pragma unroll
      for (int cd = 0; cd < 4; ++cd) {
        short8 bv = *(const short8*)(vrow + ((size_t)cd << 16) +
                                     (kt << 7) + (kk << 5));
        oacc[cd] = mfma_bf16(ap, bv, oacc[cd]);
      }
    }
  }

  // epilogue: O
#pragma unroll
  for (int cd = 0; cd < 4; ++cd)
#pragma unroll
    for (int i = 0; i < 4; ++i) {
      const int q = q0 + (wid << 4) + (lg << 2) + i;
      const int d = (cd << 4) + lr;
      __builtin_nontemporal_store(oacc[cd][i],
          outO + (((size_t)b * S_LEN + q) << 9) + h * 64 + d);
    }
}

extern "C" void kernel_launch(void* const* d_in, const int* in_sizes, int n_in,
                              void* d_out, int out_size, void* d_ws, size_t ws_size,
                              hipStream_t stream) {
  (void)in_sizes; (void)n_in; (void)out_size; (void)ws_size;
  const float* query = (const float*)d_in[0];
  const float* key_i = (const float*)d_in[1];
  const float* value = (const float*)d_in[2];
  const unsigned char* kpm = (const unsigned char*)d_in[3];
  const float* Wq = (const float*)d_in[4];
  const float* bq_ = (const float*)d_in[5];
  const float* Wk = (const float*)d_in[6];
  const float* bk_ = (const float*)d_in[7];
  const float* Wv = (const float*)d_in[8];
  const float* bv_ = (const float*)d_in[9];

  u16* Qp = (u16*)d_ws;                                  // [16][4096][64] bf16
  u16* Kp = Qp + (size_t)NB * NHD * S_LEN * 64;          // [16][4096][64] bf16
  u16* Vt = Kp + (size_t)NB * NHD * S_LEN * 64;          // [16][64][4096] bf16

  float* outO = (float*)d_out;
  float* outW = outO + (size_t)NB * S_LEN * HID;

  dim3 pg(64, 4), pb(256);
  // scale 1/sqrt(64) folded into Q projection
  proj_kernel<<<pg, pb, 0, stream>>>(query, Wq, bq_, Qp, 0, 0.125f);
  proj_kernel<<<pg, pb, 0, stream>>>(key_i, Wk, bk_, Kp, 0, 1.0f);
  proj_kernel<<<pg, pb, 0, stream>>>(value, Wv, bv_, Vt, 1, 1.0f);
  attn_kernel<<<dim3(1024), dim3(256), 0, stream>>>(Qp, Kp, Vt, kpm, outO, outW);
}

// Round 3
// 510.851 us; speedup vs baseline: 2.2082x; 2.2082x over previous
//
#include <hip/hip_runtime.h>

typedef __attribute__((ext_vector_type(4))) float f32x4;
typedef __attribute__((ext_vector_type(8))) short short8;
typedef __attribute__((ext_vector_type(8))) __bf16 bf16x8;
typedef __attribute__((ext_vector_type(4))) unsigned int u32x4;
typedef __attribute__((ext_vector_type(4))) unsigned short u16x4;
typedef unsigned short u16;
typedef unsigned int u32;

#define NB 2
#define S_LEN 4096
#define NHD 8
#define HID 512

__device__ __forceinline__ u16 f2bf(float f) {
  u32 u = __builtin_bit_cast(u32, f);
  u += 0x7fffu + ((u >> 16) & 1u);   // round-to-nearest-even
  return (u16)(u >> 16);
}

// MFMA wrapper hedged over the two plausible builtin signatures (V8s vs V8y).
template <typename V>
static __device__ __forceinline__ auto mfma_imp(V a, V b, f32x4 c, int)
    -> decltype(__builtin_amdgcn_mfma_f32_16x16x32_bf16(a, b, c, 0, 0, 0)) {
  return __builtin_amdgcn_mfma_f32_16x16x32_bf16(a, b, c, 0, 0, 0);
}
template <typename V>
static __device__ __forceinline__ f32x4 mfma_imp(V a, V b, f32x4 c, long) {
  return __builtin_amdgcn_mfma_f32_16x16x32_bf16(
      __builtin_bit_cast(bf16x8, a), __builtin_bit_cast(bf16x8, b), c, 0, 0, 0);
}
static __device__ __forceinline__ f32x4 mfma_bf16(short8 a, short8 b, f32x4 c) {
  return mfma_imp(a, b, c, 0);
}

// Raw workgroup barrier that does NOT drain vmcnt: own LDS ops flushed
// (lgkmcnt 0), scheduler pinned (rule 18), then s_barrier. Global loads and
// the nontemporal W-store stream stay in flight across it.
#define WG_BARRIER()                                        \
  do {                                                      \
    asm volatile("s_waitcnt lgkmcnt(0)" ::: "memory");      \
    __builtin_amdgcn_sched_barrier(0);                      \
    __builtin_amdgcn_s_barrier();                           \
    __builtin_amdgcn_sched_barrier(0);                      \
  } while (0)

// ---------------------------------------------------------------------------
// Projection GEMM: C[i][j] = sum_k X[i][k] * W[j][k] + bias[j], scaled, ->bf16
// out layout: transposeOut==0 : [(b*8+h)][s][64]   (Q, K)
//             transposeOut==1 : [(b*8+h)][64][s]   (V^T, so PV B-operand is contiguous)
// ---------------------------------------------------------------------------
__global__ __launch_bounds__(256, 2) void proj_kernel(
    const float* __restrict__ X, const float* __restrict__ W,
    const float* __restrict__ bias, u16* __restrict__ out,
    const int transposeOut, const float scale)
{
  __shared__ u16 Al[128 * 64];
  __shared__ u16 Bl[128 * 64];
  const int tid = threadIdx.x;
  const int lane = tid & 63;
  const int wid = tid >> 6;
  const int wr = (wid >> 1) << 6;
  const int wc = (wid & 1) << 6;
  const int bm = blockIdx.x << 7;
  const int bn = blockIdx.y << 7;

  f32x4 acc[4][4] = {};

#pragma unroll 1
  for (int k0 = 0; k0 < HID; k0 += 64) {
    __syncthreads();
#pragma unroll
    for (int i = 0; i < 4; ++i) {
      const int idx = i * 256 + tid;
      const int row = idx >> 3;     // 8 chunks of 8 elems per 64-wide row
      const int c = idx & 7;
      const int off = (row * 128 + c * 16) ^ ((row & 7) << 4);
      const float* ga = X + (size_t)(bm + row) * HID + k0 + c * 8;
      f32x4 a0 = *(const f32x4*)ga;
      f32x4 a1 = *(const f32x4*)(ga + 4);
      short8 pa;
      pa[0] = (short)f2bf(a0[0]); pa[1] = (short)f2bf(a0[1]);
      pa[2] = (short)f2bf(a0[2]); pa[3] = (short)f2bf(a0[3]);
      pa[4] = (short)f2bf(a1[0]); pa[5] = (short)f2bf(a1[1]);
      pa[6] = (short)f2bf(a1[2]); pa[7] = (short)f2bf(a1[3]);
      *(short8*)((char*)Al + off) = pa;
      const float* gb = W + (size_t)(bn + row) * HID + k0 + c * 8;
      f32x4 b0 = *(const f32x4*)gb;
      f32x4 b1 = *(const f32x4*)(gb + 4);
      short8 pb;
      pb[0] = (short)f2bf(b0[0]); pb[1] = (short)f2bf(b0[1]);
      pb[2] = (short)f2bf(b0[2]); pb[3] = (short)f2bf(b0[3]);
      pb[4] = (short)f2bf(b1[0]); pb[5] = (short)f2bf(b1[1]);
      pb[6] = (short)f2bf(b1[2]); pb[7] = (short)f2bf(b1[3]);
      *(short8*)((char*)Bl + off) = pb;
    }
    __syncthreads();
#pragma unroll
    for (int ks = 0; ks < 2; ++ks) {
      const int koffb = (ks * 32 + ((lane >> 4) << 3)) * 2;
      short8 af[4], bfr[4];
#pragma unroll
      for (int m = 0; m < 4; ++m) {
        const int row = wr + m * 16 + (lane & 15);
        af[m] = *(const short8*)((const char*)Al + ((row * 128 + koffb) ^ ((row & 7) << 4)));
      }
#pragma unroll
      for (int n = 0; n < 4; ++n) {
        const int row = wc + n * 16 + (lane & 15);
        bfr[n] = *(const short8*)((const char*)Bl + ((row * 128 + koffb) ^ ((row & 7) << 4)));
      }
#pragma unroll
      for (int m = 0; m < 4; ++m)
#pragma unroll
        for (int n = 0; n < 4; ++n)
          acc[m][n] = mfma_bf16(af[m], bfr[n], acc[m][n]);
    }
  }

#pragma unroll
  for (int n = 0; n < 4; ++n) {
    const int j = bn + wc + n * 16 + (lane & 15);
    const float bj = bias[j];
    const int h = j >> 6, d = j & 63;
#pragma unroll
    for (int m = 0; m < 4; ++m) {
      const int rbase = bm + wr + m * 16 + ((lane >> 4) << 2);
      const int b = rbase >> 12;
      const int s = rbase & (S_LEN - 1);
      if (!transposeOut) {
#pragma unroll
        for (int i = 0; i < 4; ++i) {
          const float v = (acc[m][n][i] + bj) * scale;
          out[(((size_t)(b * NHD + h) * S_LEN + (s + i)) << 6) + d] = f2bf(v);
        }
      } else {
        u16x4 pk;
#pragma unroll
        for (int i = 0; i < 4; ++i) pk[i] = f2bf((acc[m][n][i] + bj) * scale);
        *(u16x4*)(out + (((size_t)(b * NHD + h) * 64 + d) << 12) + s) = pk;
      }
    }
  }
}

// ---------------------------------------------------------------------------
// Fused attention, pipelined LDS staging (T14 async split + counted vmcnt).
// One WG per (b*8+h, 128-row q-tile); 4 waves x 32 q-rows; grid 512 (2 WG/CU).
// Per kt-tile: compute on LDS tile kt, raw-barrier, ds_write register-staged
// tile kt+1 (compiler emits a COUNTED vmcnt for those loads — the nontemporal
// W-store stream is never drained), issue global loads for tile kt+2,
// raw-barrier. Stage-load latency hides under a full compute phase; stores
// stream continuously at HBM rate.
// Swapped QK^T: S^T = K·Q^T so C-frag holds 4 consecutive KEYS per lane.
// Pass A: softmax denominators. Pass B: recompute S, write normalized W
// (fp32, nontemporal), accumulate O = P·V via wave-private LDS P.
// ---------------------------------------------------------------------------
__global__ __launch_bounds__(256, 2) void attn_kernel(
    const u16* __restrict__ Qp, const u16* __restrict__ Kp,
    const u16* __restrict__ Vt, const unsigned char* __restrict__ mask,
    float* __restrict__ outO, float* __restrict__ outW)
{
  __shared__ u16 Kl[128 * 64];      // K tile (16 KB)
  __shared__ u16 Vl[128 * 64];      // Q tile during prologue; V^T tile in pass B
  __shared__ u16 Pl[4][32 * 128];   // per-wave normalized P (bf16, swizzled)
  __shared__ u32 anyMaskSh;

  const int tid = threadIdx.x;
  const int lane = tid & 63;
  const int wid = tid >> 6;
  const int lr = lane & 15;
  const int lg = lane >> 4;

  // XCD-bijective swizzle: 512 blocks; each XCD gets a 64-block chunk = 2
  // heads (K+V+Q = 3 MB fits the 4 MB per-XCD L2).
  const int bid = blockIdx.x;
  const int swz = (bid & 7) * 64 + (bid >> 3);
  const int bh = swz >> 5;          // b*8 + h
  const int q0 = (swz & 31) << 7;
  const int b = bh >> 3;
  const int h = bh & 7;

  // per-thread staging offsets (K tile: [128][64] rows; V tile: [64][128] keys)
  int koff[4], kgo[4], voff[4], vgo[4];
#pragma unroll
  for (int i = 0; i < 4; ++i) {
    const int idx = i * 256 + tid;
    const int kr = idx >> 3, kc = idx & 7;
    koff[i] = (kr * 128 + kc * 16) ^ ((kr & 7) << 4);
    kgo[i] = (kr << 6) + kc * 8;
    const int vr = idx >> 4, vc = idx & 15;
    voff[i] = (vr * 256 + vc * 16) ^ ((vr & 7) << 4);
    vgo[i] = (vr << 12) + vc * 8;
  }
  const u16* kgbase = Kp + ((size_t)bh << 18);
  const u16* vgbase = Vt + ((size_t)bh << 18);

  if (tid == 0) anyMaskSh = 0u;
  __syncthreads();
  // stage Q tile (swizzled, into Vl) + mask scan
#pragma unroll
  for (int i = 0; i < 4; ++i) {
    const int idx = i * 256 + tid;
    const int row = idx >> 3;
    const int c = idx & 7;
    u32x4 v = *(const u32x4*)(Qp + (((size_t)bh * S_LEN + q0 + row) << 6) + c * 8);
    *(u32x4*)((char*)Vl + ((row * 128 + c * 16) ^ ((row & 7) << 4))) = v;
  }
  {
    u32x4 mv = *(const u32x4*)(mask + (size_t)b * S_LEN + tid * 16);
    if (mv[0] | mv[1] | mv[2] | mv[3]) atomicOr(&anyMaskSh, 1u);
  }
  __syncthreads();
  const bool anyMask = (anyMaskSh != 0u);

  // hoist Q fragments (MFMA B operand) — constant for the whole kernel
  short8 bq[2][2];
#pragma unroll
  for (int cb = 0; cb < 2; ++cb)
#pragma unroll
    for (int ks = 0; ks < 2; ++ks) {
      const int qrow = (wid << 5) + (cb << 4) + lr;
      bq[cb][ks] = *(const short8*)((const char*)Vl +
          ((qrow * 128 + (ks * 32 + (lg << 3)) * 2) ^ ((qrow & 7) << 4)));
    }
  __syncthreads();   // all waves have bq; Vl free for reuse (safe: no stores yet)

  u32x4 rK[4], rV[4];

  // ---------------- pass A: softmax denominators ----------------
  // prologue: tile0 -> LDS, tile1 -> regs
#pragma unroll
  for (int i = 0; i < 4; ++i) rK[i] = *(const u32x4*)(kgbase + kgo[i]);
#pragma unroll
  for (int i = 0; i < 4; ++i) *(u32x4*)((char*)Kl + koff[i]) = rK[i];
#pragma unroll
  for (int i = 0; i < 4; ++i) rK[i] = *(const u32x4*)(kgbase + (1 << 13) + kgo[i]);
  WG_BARRIER();

  float lsum[2] = {0.f, 0.f};
#pragma unroll 1
  for (int kt = 0; kt < 32; ++kt) {
#pragma unroll
    for (int rb = 0; rb < 8; ++rb) {
      short8 ak[2];
#pragma unroll
      for (int ks = 0; ks < 2; ++ks) {
        const int krow = (rb << 4) + lr;
        ak[ks] = *(const short8*)((const char*)Kl +
            ((krow * 128 + (ks * 32 + (lg << 3)) * 2) ^ ((krow & 7) << 4)));
      }
      u32 mw = 0u;
      if (anyMask)
        mw = *(const u32*)(mask + (size_t)b * S_LEN + (kt << 7) + (rb << 4) + (lg << 2));
#pragma unroll
      for (int cb = 0; cb < 2; ++cb) {
        f32x4 sv = {};
        sv = mfma_bf16(ak[0], bq[cb][0], sv);
        sv = mfma_bf16(ak[1], bq[cb][1], sv);
        float p0 = __expf(sv[0]);
        float p1 = __expf(sv[1]);
        float p2 = __expf(sv[2]);
        float p3 = __expf(sv[3]);
        if (mw) {
          if (mw & 0x000000FFu) p0 = 0.f;
          if (mw & 0x0000FF00u) p1 = 0.f;
          if (mw & 0x00FF0000u) p2 = 0.f;
          if (mw & 0xFF000000u) p3 = 0.f;
        }
        lsum[cb] += (p0 + p1) + (p2 + p3);
      }
    }
    WG_BARRIER();                    // all waves done reading Kl tile kt
    if (kt < 31) {
#pragma unroll
      for (int i = 0; i < 4; ++i) *(u32x4*)((char*)Kl + koff[i]) = rK[i];
    }
    if (kt < 30) {
#pragma unroll
      for (int i = 0; i < 4; ++i)
        rK[i] = *(const u32x4*)(kgbase + ((size_t)(kt + 2) << 13) + kgo[i]);
    }
    WG_BARRIER();                    // tile kt+1 visible to all
  }

  float inv[2];
#pragma unroll
  for (int cb = 0; cb < 2; ++cb) {
    float t = lsum[cb];
    t += __shfl_xor(t, 16);
    t += __shfl_xor(t, 32);
    inv[cb] = 1.0f / t;
  }

  // ---------------- pass B: weights out + O = P·V ----------------
  // prologue: tile0 -> LDS (K and V), tile1 -> regs
#pragma unroll
  for (int i = 0; i < 4; ++i) {
    rK[i] = *(const u32x4*)(kgbase + kgo[i]);
    rV[i] = *(const u32x4*)(vgbase + vgo[i]);
  }
#pragma unroll
  for (int i = 0; i < 4; ++i) {
    *(u32x4*)((char*)Kl + koff[i]) = rK[i];
    *(u32x4*)((char*)Vl + voff[i]) = rV[i];
  }
#pragma unroll
  for (int i = 0; i < 4; ++i) {
    rK[i] = *(const u32x4*)(kgbase + (1 << 13) + kgo[i]);
    rV[i] = *(const u32x4*)(vgbase + (1 << 7) + vgo[i]);
  }
  WG_BARRIER();

  f32x4 oacc[2][4] = {};
#pragma unroll 1
  for (int kt = 0; kt < 32; ++kt) {
#pragma unroll
    for (int rb = 0; rb < 8; ++rb) {
      short8 ak[2];
#pragma unroll
      for (int ks = 0; ks < 2; ++ks) {
        const int krow = (rb << 4) + lr;
        ak[ks] = *(const short8*)((const char*)Kl +
            ((krow * 128 + (ks * 32 + (lg << 3)) * 2) ^ ((krow & 7) << 4)));
      }
      u32 mw = 0u;
      if (anyMask)
        mw = *(const u32*)(mask + (size_t)b * S_LEN + (kt << 7) + (rb << 4) + (lg << 2));
#pragma unroll
      for (int cb = 0; cb < 2; ++cb) {
        f32x4 sv = {};
        sv = mfma_bf16(ak[0], bq[cb][0], sv);
        sv = mfma_bf16(ak[1], bq[cb][1], sv);
        float p0 = __expf(sv[0]) * inv[cb];
        float p1 = __expf(sv[1]) * inv[cb];
        float p2 = __expf(sv[2]) * inv[cb];
        float p3 = __expf(sv[3]) * inv[cb];
        if (mw) {
          if (mw & 0x000000FFu) p0 = 0.f;
          if (mw & 0x0000FF00u) p1 = 0.f;
          if (mw & 0x00FF0000u) p2 = 0.f;
          if (mw & 0xFF000000u) p3 = 0.f;
        }
        f32x4 wv; wv[0] = p0; wv[1] = p1; wv[2] = p2; wv[3] = p3;
        const int q = q0 + (wid << 5) + (cb << 4) + lr;
        const int key = (kt << 7) + (rb << 4) + (lg << 2);
        __builtin_nontemporal_store(wv,
            (f32x4*)(outW + (((size_t)bh * S_LEN + q) << 12) + key));
        u16x4 pk;
        pk[0] = f2bf(p0); pk[1] = f2bf(p1); pk[2] = f2bf(p2); pk[3] = f2bf(p3);
        const int ql = (cb << 4) + lr;
        *(u16x4*)((char*)Pl[wid] +
            ((ql * 256 + (((rb << 4) + (lg << 2)) * 2)) ^ ((ql & 7) << 4))) = pk;
      }
    }
    // PV: P is wave-private (same-wave in-order LDS RAW — no barrier needed)
#pragma unroll
    for (int kk = 0; kk < 4; ++kk) {
      const int koffb = (kk * 32 + (lg << 3)) * 2;
      short8 ap[2];
#pragma unroll
      for (int rq = 0; rq < 2; ++rq) {
        const int qrow = (rq << 4) + lr;
        ap[rq] = *(const short8*)((const char*)Pl[wid] +
            ((qrow * 256 + koffb) ^ ((qrow & 7) << 4)));
      }
#pragma unroll
      for (int cd = 0; cd < 4; ++cd) {
        const int drow = (cd << 4) + lr;
        short8 bv = *(const short8*)((const char*)Vl +
            ((drow * 256 + koffb) ^ ((drow & 7) << 4)));
        oacc[0][cd] = mfma_bf16(ap[0], bv, oacc[0][cd]);
        oacc[1][cd] = mfma_bf16(ap[1], bv, oacc[1][cd]);
      }
    }
    WG_BARRIER();                    // all waves done reading Kl/Vl tile kt
    if (kt < 31) {
#pragma unroll
      for (int i = 0; i < 4; ++i) {
        *(u32x4*)((char*)Kl + koff[i]) = rK[i];   // counted vmcnt: W stores not drained
        *(u32x4*)((char*)Vl + voff[i]) = rV[i];
      }
    }
    if (kt < 30) {
#pragma unroll
      for (int i = 0; i < 4; ++i) {
        rK[i] = *(const u32x4*)(kgbase + ((size_t)(kt + 2) << 13) + kgo[i]);
        rV[i] = *(const u32x4*)(vgbase + ((size_t)(kt + 2) << 7) + vgo[i]);
      }
    }
    WG_BARRIER();                    // tile kt+1 visible to all
  }

  // epilogue: O
#pragma unroll
  for (int rq = 0; rq < 2; ++rq)
#pragma unroll
    for (int cd = 0; cd < 4; ++cd)
#pragma unroll
      for (int i = 0; i < 4; ++i) {
        const int q = q0 + (wid << 5) + (rq << 4) + (lg << 2) + i;
        const int d = (cd << 4) + lr;
        __builtin_nontemporal_store(oacc[rq][cd][i],
            outO + (((size_t)b * S_LEN + q) << 9) + h * 64 + d);
      }
}

extern "C" void kernel_launch(void* const* d_in, const int* in_sizes, int n_in,
                              void* d_out, int out_size, void* d_ws, size_t ws_size,
                              hipStream_t stream) {
  (void)in_sizes; (void)n_in; (void)out_size; (void)ws_size;
  const float* query = (const float*)d_in[0];
  const float* key_i = (const float*)d_in[1];
  const float* value = (const float*)d_in[2];
  const unsigned char* kpm = (const unsigned char*)d_in[3];
  const float* Wq = (const float*)d_in[4];
  const float* bq_ = (const float*)d_in[5];
  const float* Wk = (const float*)d_in[6];
  const float* bk_ = (const float*)d_in[7];
  const float* Wv = (const float*)d_in[8];
  const float* bv_ = (const float*)d_in[9];

  u16* Qp = (u16*)d_ws;                                  // [16][4096][64] bf16
  u16* Kp = Qp + (size_t)NB * NHD * S_LEN * 64;          // [16][4096][64] bf16
  u16* Vt = Kp + (size_t)NB * NHD * S_LEN * 64;          // [16][64][4096] bf16

  float* outO = (float*)d_out;
  float* outW = outO + (size_t)NB * S_LEN * HID;

  dim3 pg(64, 4), pb(256);
  // scale 1/sqrt(64) folded into Q projection
  proj_kernel<<<pg, pb, 0, stream>>>(query, Wq, bq_, Qp, 0, 0.125f);
  proj_kernel<<<pg, pb, 0, stream>>>(key_i, Wk, bk_, Kp, 0, 1.0f);
  proj_kernel<<<pg, pb, 0, stream>>>(value, Wv, bv_, Vt, 1, 1.0f);
  attn_kernel<<<dim3(512), dim3(256), 0, stream>>>(Qp, Kp, Vt, kpm, outO, outW);
}

// Round 4
// 433.832 us; speedup vs baseline: 2.6002x; 1.1775x over previous
//
#include <hip/hip_runtime.h>

typedef __attribute__((ext_vector_type(4))) float f32x4;
typedef __attribute__((ext_vector_type(8))) short short8;
typedef __attribute__((ext_vector_type(8))) __bf16 bf16x8;
typedef __attribute__((ext_vector_type(4))) unsigned int u32x4;
typedef __attribute__((ext_vector_type(4))) unsigned short u16x4;
typedef unsigned short u16;
typedef unsigned int u32;

#define NB 2
#define S_LEN 4096
#define NHD 8
#define HID 512

__device__ __forceinline__ u16 f2bf(float f) {
  u32 u = __builtin_bit_cast(u32, f);
  u += 0x7fffu + ((u >> 16) & 1u);   // round-to-nearest-even
  return (u16)(u >> 16);
}

// MFMA wrapper hedged over the two plausible builtin signatures (V8s vs V8y).
template <typename V>
static __device__ __forceinline__ auto mfma_imp(V a, V b, f32x4 c, int)
    -> decltype(__builtin_amdgcn_mfma_f32_16x16x32_bf16(a, b, c, 0, 0, 0)) {
  return __builtin_amdgcn_mfma_f32_16x16x32_bf16(a, b, c, 0, 0, 0);
}
template <typename V>
static __device__ __forceinline__ f32x4 mfma_imp(V a, V b, f32x4 c, long) {
  return __builtin_amdgcn_mfma_f32_16x16x32_bf16(
      __builtin_bit_cast(bf16x8, a), __builtin_bit_cast(bf16x8, b), c, 0, 0, 0);
}
static __device__ __forceinline__ f32x4 mfma_bf16(short8 a, short8 b, f32x4 c) {
  return mfma_imp(a, b, c, 0);
}

// Raw workgroup barrier that does NOT drain vmcnt: own LDS ops flushed
// (lgkmcnt 0), scheduler pinned (rule 18), then s_barrier. Global loads and
// the nontemporal W-store stream stay in flight across it.
#define WG_BARRIER()                                        \
  do {                                                      \
    asm volatile("s_waitcnt lgkmcnt(0)" ::: "memory");      \
    __builtin_amdgcn_sched_barrier(0);                      \
    __builtin_amdgcn_s_barrier();                           \
    __builtin_amdgcn_sched_barrier(0);                      \
  } while (0)

// ---------------------------------------------------------------------------
// Fused projection GEMM (Q, K, V in one launch via blockIdx.z):
// C[i][j] = sum_k X[i][k] * W[j][k] + bias[j], scaled, ->bf16
// z==0 (Q): out [(b*8+h)][s][64], scale 0.125 (1/sqrt(64) folded in)
// z==1 (K): out [(b*8+h)][s][64]
// z==2 (V): out [(b*8+h)][64][s]  (V^T so PV B-operand is contiguous)
// ---------------------------------------------------------------------------
__global__ __launch_bounds__(256, 2) void proj_kernel(
    const float* __restrict__ Xq, const float* __restrict__ Xk,
    const float* __restrict__ Xv, const float* __restrict__ Wq,
    const float* __restrict__ Wk, const float* __restrict__ Wv,
    const float* __restrict__ bq_, const float* __restrict__ bk_,
    const float* __restrict__ bv_, u16* __restrict__ oq,
    u16* __restrict__ ok, u16* __restrict__ ov)
{
  __shared__ u16 Al[128 * 64];
  __shared__ u16 Bl[128 * 64];
  const int z = blockIdx.z;
  const float* X = (z == 0) ? Xq : (z == 1) ? Xk : Xv;
  const float* W = (z == 0) ? Wq : (z == 1) ? Wk : Wv;
  const float* bias = (z == 0) ? bq_ : (z == 1) ? bk_ : bv_;
  u16* out = (z == 0) ? oq : (z == 1) ? ok : ov;
  const int transposeOut = (z == 2);
  const float scale = (z == 0) ? 0.125f : 1.0f;

  const int tid = threadIdx.x;
  const int lane = tid & 63;
  const int wid = tid >> 6;
  const int wr = (wid >> 1) << 6;
  const int wc = (wid & 1) << 6;
  const int bm = blockIdx.x << 7;
  const int bn = blockIdx.y << 7;

  f32x4 acc[4][4] = {};

#pragma unroll 1
  for (int k0 = 0; k0 < HID; k0 += 64) {
    __syncthreads();
#pragma unroll
    for (int i = 0; i < 4; ++i) {
      const int idx = i * 256 + tid;
      const int row = idx >> 3;     // 8 chunks of 8 elems per 64-wide row
      const int c = idx & 7;
      const int off = (row * 128 + c * 16) ^ ((row & 7) << 4);
      const float* ga = X + (size_t)(bm + row) * HID + k0 + c * 8;
      f32x4 a0 = *(const f32x4*)ga;
      f32x4 a1 = *(const f32x4*)(ga + 4);
      short8 pa;
      pa[0] = (short)f2bf(a0[0]); pa[1] = (short)f2bf(a0[1]);
      pa[2] = (short)f2bf(a0[2]); pa[3] = (short)f2bf(a0[3]);
      pa[4] = (short)f2bf(a1[0]); pa[5] = (short)f2bf(a1[1]);
      pa[6] = (short)f2bf(a1[2]); pa[7] = (short)f2bf(a1[3]);
      *(short8*)((char*)Al + off) = pa;
      const float* gb = W + (size_t)(bn + row) * HID + k0 + c * 8;
      f32x4 b0 = *(const f32x4*)gb;
      f32x4 b1 = *(const f32x4*)(gb + 4);
      short8 pb;
      pb[0] = (short)f2bf(b0[0]); pb[1] = (short)f2bf(b0[1]);
      pb[2] = (short)f2bf(b0[2]); pb[3] = (short)f2bf(b0[3]);
      pb[4] = (short)f2bf(b1[0]); pb[5] = (short)f2bf(b1[1]);
      pb[6] = (short)f2bf(b1[2]); pb[7] = (short)f2bf(b1[3]);
      *(short8*)((char*)Bl + off) = pb;
    }
    __syncthreads();
#pragma unroll
    for (int ks = 0; ks < 2; ++ks) {
      const int koffb = (ks * 32 + ((lane >> 4) << 3)) * 2;
      short8 af[4], bfr[4];
#pragma unroll
      for (int m = 0; m < 4; ++m) {
        const int row = wr + m * 16 + (lane & 15);
        af[m] = *(const short8*)((const char*)Al + ((row * 128 + koffb) ^ ((row & 7) << 4)));
      }
#pragma unroll
      for (int n = 0; n < 4; ++n) {
        const int row = wc + n * 16 + (lane & 15);
        bfr[n] = *(const short8*)((const char*)Bl + ((row * 128 + koffb) ^ ((row & 7) << 4)));
      }
#pragma unroll
      for (int m = 0; m < 4; ++m)
#pragma unroll
        for (int n = 0; n < 4; ++n)
          acc[m][n] = mfma_bf16(af[m], bfr[n], acc[m][n]);
    }
  }

#pragma unroll
  for (int n = 0; n < 4; ++n) {
    const int j = bn + wc + n * 16 + (lane & 15);
    const float bj = bias[j];
    const int h = j >> 6, d = j & 63;
#pragma unroll
    for (int m = 0; m < 4; ++m) {
      const int rbase = bm + wr + m * 16 + ((lane >> 4) << 2);
      const int b = rbase >> 12;
      const int s = rbase & (S_LEN - 1);
      if (!transposeOut) {
#pragma unroll
        for (int i = 0; i < 4; ++i) {
          const float v = (acc[m][n][i] + bj) * scale;
          out[(((size_t)(b * NHD + h) * S_LEN + (s + i)) << 6) + d] = f2bf(v);
        }
      } else {
        u16x4 pk;
#pragma unroll
        for (int i = 0; i < 4; ++i) pk[i] = f2bf((acc[m][n][i] + bj) * scale);
        *(u16x4*)(out + (((size_t)(b * NHD + h) * 64 + d) << 12) + s) = pk;
      }
    }
  }
}

// ---------------------------------------------------------------------------
// Fused attention, q-tile-pair pipelined so the softmax-denominator pass is
// hidden under the W-store stream.
// One WG per (b*8+h, 128 q-rows) = two 64-row tiles t0,t1; 4 waves x 16
// q-rows per tile. Three phases over the same K/V tiles (round-2 pipelined
// staging with non-draining barriers in each):
//   A0:      denominators for t0 only              (store pipe idle — short)
//   phase 1: pass B for t0  +  denominators for t1 (A-part hides under stores;
//            K fragments shared by both since K rows are q-independent)
//   phase 2: pass B for t1
// Pass B: recompute S, write normalized W (fp32, nontemporal), O = P·V via
// wave-private LDS P. Swapped QK^T: C-frag holds 4 consecutive KEYS per lane.
// ---------------------------------------------------------------------------
__global__ __launch_bounds__(256, 2) void attn_kernel(
    const u16* __restrict__ Qp, const u16* __restrict__ Kp,
    const u16* __restrict__ Vt, const unsigned char* __restrict__ mask,
    float* __restrict__ outO, float* __restrict__ outW)
{
  __shared__ u16 Kl[128 * 64];      // K tile (16 KB)
  __shared__ u16 Vl[64 * 128];      // V^T tile (16 KB)
  __shared__ u16 Pl[4][16 * 128];   // per-wave normalized P (16 KB total)
  __shared__ u32 anyMaskSh;

  const int tid = threadIdx.x;
  const int lane = tid & 63;
  const int wid = tid >> 6;
  const int lr = lane & 15;
  const int lg = lane >> 4;

  // XCD-bijective swizzle: 512 blocks; each XCD gets a 64-block chunk = 2
  // heads (K+V+Q = 3 MB fits the 4 MB per-XCD L2).
  const int bid = blockIdx.x;
  const int swz = (bid & 7) * 64 + (bid >> 3);
  const int bh = swz >> 5;          // b*8 + h
  const int q0 = (swz & 31) << 7;   // 128 q-rows = tiles t0,t1
  const int b = bh >> 3;
  const int h = bh & 7;

  // per-thread staging offsets (K tile: [128][64]; V tile: [64][128] keys)
  int koff[4], kgo[4], voff[4], vgo[4];
#pragma unroll
  for (int i = 0; i < 4; ++i) {
    const int idx = i * 256 + tid;
    const int kr = idx >> 3, kc = idx & 7;
    koff[i] = (kr * 128 + kc * 16) ^ ((kr & 7) << 4);
    kgo[i] = (kr << 6) + kc * 8;
    const int vr = idx >> 4, vc = idx & 15;
    voff[i] = (vr * 256 + vc * 16) ^ ((vr & 7) << 4);
    vgo[i] = (vr << 12) + vc * 8;
  }
  const u16* kgbase = Kp + ((size_t)bh << 18);
  const u16* vgbase = Vt + ((size_t)bh << 18);

  if (tid == 0) anyMaskSh = 0u;
  __syncthreads();
  {
    u32x4 mv = *(const u32x4*)(mask + (size_t)b * S_LEN + tid * 16);
    if (mv[0] | mv[1] | mv[2] | mv[3]) atomicOr(&anyMaskSh, 1u);
  }
  __syncthreads();
  const bool anyMask = (anyMaskSh != 0u);

  // Q fragments (MFMA B operand) for both tiles, straight from global (one-time)
  short8 bq[2][2];
#pragma unroll
  for (int t = 0; t < 2; ++t)
#pragma unroll
    for (int ks = 0; ks < 2; ++ks) {
      const int qr = q0 + (t << 6) + (wid << 4) + lr;
      bq[t][ks] = *(const short8*)(
          Qp + (((size_t)bh * S_LEN + qr) << 6) + ks * 32 + lg * 8);
    }

  const unsigned char* mrow = mask + (size_t)b * S_LEN + (lg << 2);
  u32x4 rK[4], rV[4];

  // ---------------- phase A0: denominators for t0 ----------------
#pragma unroll
  for (int i = 0; i < 4; ++i) rK[i] = *(const u32x4*)(kgbase + kgo[i]);
#pragma unroll
  for (int i = 0; i < 4; ++i) *(u32x4*)((char*)Kl + koff[i]) = rK[i];
#pragma unroll
  for (int i = 0; i < 4; ++i) rK[i] = *(const u32x4*)(kgbase + (1 << 13) + kgo[i]);
  WG_BARRIER();

  float lsum0 = 0.f;
#pragma unroll 1
  for (int kt = 0; kt < 32; ++kt) {
#pragma unroll
    for (int rb = 0; rb < 8; ++rb) {
      const int krow = (rb << 4) + lr;
      short8 ak0 = *(const short8*)((const char*)Kl +
          ((krow * 128 + (lg << 4)) ^ ((krow & 7) << 4)));
      short8 ak1 = *(const short8*)((const char*)Kl +
          ((krow * 128 + 64 + (lg << 4)) ^ ((krow & 7) << 4)));
      u32 mw = 0u;
      if (anyMask) mw = *(const u32*)(mrow + (kt << 7) + (rb << 4));
      f32x4 sv = {};
      sv = mfma_bf16(ak0, bq[0][0], sv);
      sv = mfma_bf16(ak1, bq[0][1], sv);
      float p0 = __expf(sv[0]);
      float p1 = __expf(sv[1]);
      float p2 = __expf(sv[2]);
      float p3 = __expf(sv[3]);
      if (mw) {
        if (mw & 0x000000FFu) p0 = 0.f;
        if (mw & 0x0000FF00u) p1 = 0.f;
        if (mw & 0x00FF0000u) p2 = 0.f;
        if (mw & 0xFF000000u) p3 = 0.f;
      }
      lsum0 += (p0 + p1) + (p2 + p3);
    }
    WG_BARRIER();
    if (kt < 31) {
#pragma unroll
      for (int i = 0; i < 4; ++i) *(u32x4*)((char*)Kl + koff[i]) = rK[i];
    }
    if (kt < 30) {
#pragma unroll
      for (int i = 0; i < 4; ++i)
        rK[i] = *(const u32x4*)(kgbase + ((size_t)(kt + 2) << 13) + kgo[i]);
    }
    WG_BARRIER();
  }
  float inv0;
  {
    float t = lsum0;
    t += __shfl_xor(t, 16);
    t += __shfl_xor(t, 32);
    inv0 = 1.0f / t;
  }

  // ---------------- phase 1: B(t0) + A(t1) ----------------
#pragma unroll
  for (int i = 0; i < 4; ++i) {
    rK[i] = *(const u32x4*)(kgbase + kgo[i]);
    rV[i] = *(const u32x4*)(vgbase + vgo[i]);
  }
#pragma unroll
  for (int i = 0; i < 4; ++i) {
    *(u32x4*)((char*)Kl + koff[i]) = rK[i];
    *(u32x4*)((char*)Vl + voff[i]) = rV[i];
  }
#pragma unroll
  for (int i = 0; i < 4; ++i) {
    rK[i] = *(const u32x4*)(kgbase + (1 << 13) + kgo[i]);
    rV[i] = *(const u32x4*)(vgbase + (1 << 7) + vgo[i]);
  }
  WG_BARRIER();

  float lsum1 = 0.f;
  f32x4 oacc[4] = {};
  float* wrow0 = outW + (((size_t)bh * S_LEN + q0 + (wid << 4) + lr) << 12) + (lg << 2);
#pragma unroll 1
  for (int kt = 0; kt < 32; ++kt) {
#pragma unroll
    for (int rb = 0; rb < 8; ++rb) {
      const int krow = (rb << 4) + lr;
      short8 ak0 = *(const short8*)((const char*)Kl +
          ((krow * 128 + (lg << 4)) ^ ((krow & 7) << 4)));
      short8 ak1 = *(const short8*)((const char*)Kl +
          ((krow * 128 + 64 + (lg << 4)) ^ ((krow & 7) << 4)));
      u32 mw = 0u;
      if (anyMask) mw = *(const u32*)(mrow + (kt << 7) + (rb << 4));
      // B for t0
      {
        f32x4 sv = {};
        sv = mfma_bf16(ak0, bq[0][0], sv);
        sv = mfma_bf16(ak1, bq[0][1], sv);
        float p0 = __expf(sv[0]) * inv0;
        float p1 = __expf(sv[1]) * inv0;
        float p2 = __expf(sv[2]) * inv0;
        float p3 = __expf(sv[3]) * inv0;
        if (mw) {
          if (mw & 0x000000FFu) p0 = 0.f;
          if (mw & 0x0000FF00u) p1 = 0.f;
          if (mw & 0x00FF0000u) p2 = 0.f;
          if (mw & 0xFF000000u) p3 = 0.f;
        }
        f32x4 wv; wv[0] = p0; wv[1] = p1; wv[2] = p2; wv[3] = p3;
        __builtin_nontemporal_store(wv, (f32x4*)(wrow0 + (kt << 7) + (rb << 4)));
        u16x4 pk;
        pk[0] = f2bf(p0); pk[1] = f2bf(p1); pk[2] = f2bf(p2); pk[3] = f2bf(p3);
        *(u16x4*)((char*)Pl[wid] +
            ((lr * 256 + (rb << 5) + (lg << 3)) ^ ((lr & 7) << 4))) = pk;
      }
      // A for t1 (same ak fragments — K rows are q-independent)
      {
        f32x4 sv = {};
        sv = mfma_bf16(ak0, bq[1][0], sv);
        sv = mfma_bf16(ak1, bq[1][1], sv);
        float p0 = __expf(sv[0]);
        float p1 = __expf(sv[1]);
        float p2 = __expf(sv[2]);
        float p3 = __expf(sv[3]);
        if (mw) {
          if (mw & 0x000000FFu) p0 = 0.f;
          if (mw & 0x0000FF00u) p1 = 0.f;
          if (mw & 0x00FF0000u) p2 = 0.f;
          if (mw & 0xFF000000u) p3 = 0.f;
        }
        lsum1 += (p0 + p1) + (p2 + p3);
      }
    }
    // PV for t0: P is wave-private (same-wave in-order LDS RAW)
#pragma unroll
    for (int kk = 0; kk < 4; ++kk) {
      short8 ap = *(const short8*)((const char*)Pl[wid] +
          ((lr * 256 + (kk << 6) + (lg << 4)) ^ ((lr & 7) << 4)));
#pragma unroll
      for (int cd = 0; cd < 4; ++cd) {
        const int drow = (cd << 4) + lr;
        short8 bv = *(const short8*)((const char*)Vl +
            ((drow * 256 + (kk << 6) + (lg << 4)) ^ ((drow & 7) << 4)));
        oacc[cd] = mfma_bf16(ap, bv, oacc[cd]);
      }
    }
    WG_BARRIER();
    if (kt < 31) {
#pragma unroll
      for (int i = 0; i < 4; ++i) {
        *(u32x4*)((char*)Kl + koff[i]) = rK[i];
        *(u32x4*)((char*)Vl + voff[i]) = rV[i];
      }
    }
    if (kt < 30) {
#pragma unroll
      for (int i = 0; i < 4; ++i) {
        rK[i] = *(const u32x4*)(kgbase + ((size_t)(kt + 2) << 13) + kgo[i]);
        rV[i] = *(const u32x4*)(vgbase + ((size_t)(kt + 2) << 7) + vgo[i]);
      }
    }
    WG_BARRIER();
  }
  float inv1;
  {
    float t = lsum1;
    t += __shfl_xor(t, 16);
    t += __shfl_xor(t, 32);
    inv1 = 1.0f / t;
  }
  // write O(t0); free oacc for t1
#pragma unroll
  for (int cd = 0; cd < 4; ++cd)
#pragma unroll
    for (int i = 0; i < 4; ++i) {
      const int q = q0 + (wid << 4) + (lg << 2) + i;
      const int d = (cd << 4) + lr;
      __builtin_nontemporal_store(oacc[cd][i],
          outO + (((size_t)b * S_LEN + q) << 9) + h * 64 + d);
      oacc[cd][i] = 0.f;
    }

  // ---------------- phase 2: B(t1) ----------------
#pragma unroll
  for (int i = 0; i < 4; ++i) {
    rK[i] = *(const u32x4*)(kgbase + kgo[i]);
    rV[i] = *(const u32x4*)(vgbase + vgo[i]);
  }
#pragma unroll
  for (int i = 0; i < 4; ++i) {
    *(u32x4*)((char*)Kl + koff[i]) = rK[i];
    *(u32x4*)((char*)Vl + voff[i]) = rV[i];
  }
#pragma unroll
  for (int i = 0; i < 4; ++i) {
    rK[i] = *(const u32x4*)(kgbase + (1 << 13) + kgo[i]);
    rV[i] = *(const u32x4*)(vgbase + (1 << 7) + vgo[i]);
  }
  WG_BARRIER();

  float* wrow1 = outW + (((size_t)bh * S_LEN + q0 + 64 + (wid << 4) + lr) << 12) + (lg << 2);
#pragma unroll 1
  for (int kt = 0; kt < 32; ++kt) {
#pragma unroll
    for (int rb = 0; rb < 8; ++rb) {
      const int krow = (rb << 4) + lr;
      short8 ak0 = *(const short8*)((const char*)Kl +
          ((krow * 128 + (lg << 4)) ^ ((krow & 7) << 4)));
      short8 ak1 = *(const short8*)((const char*)Kl +
          ((krow * 128 + 64 + (lg << 4)) ^ ((krow & 7) << 4)));
      u32 mw = 0u;
      if (anyMask) mw = *(const u32*)(mrow + (kt << 7) + (rb << 4));
      f32x4 sv = {};
      sv = mfma_bf16(ak0, bq[1][0], sv);
      sv = mfma_bf16(ak1, bq[1][1], sv);
      float p0 = __expf(sv[0]) * inv1;
      float p1 = __expf(sv[1]) * inv1;
      float p2 = __expf(sv[2]) * inv1;
      float p3 = __expf(sv[3]) * inv1;
      if (mw) {
        if (mw & 0x000000FFu) p0 = 0.f;
        if (mw & 0x0000FF00u) p1 = 0.f;
        if (mw & 0x00FF0000u) p2 = 0.f;
        if (mw & 0xFF000000u) p3 = 0.f;
      }
      f32x4 wv; wv[0] = p0; wv[1] = p1; wv[2] = p2; wv[3] = p3;
      __builtin_nontemporal_store(wv, (f32x4*)(wrow1 + (kt << 7) + (rb << 4)));
      u16x4 pk;
      pk[0] = f2bf(p0); pk[1] = f2bf(p1); pk[2] = f2bf(p2); pk[3] = f2bf(p3);
      *(u16x4*)((char*)Pl[wid] +
          ((lr * 256 + (rb << 5) + (lg << 3)) ^ ((lr & 7) << 4))) = pk;
    }
#pragma unroll
    for (int kk = 0; kk < 4; ++kk) {
      short8 ap = *(const short8*)((const char*)Pl[wid] +
          ((lr * 256 + (kk << 6) + (lg << 4)) ^ ((lr & 7) << 4)));
#pragma unroll
      for (int cd = 0; cd < 4; ++cd) {
        const int drow = (cd << 4) + lr;
        short8 bv = *(const short8*)((const char*)Vl +
            ((drow * 256 + (kk << 6) + (lg << 4)) ^ ((drow & 7) << 4)));
        oacc[cd] = mfma_bf16(ap, bv, oacc[cd]);
      }
    }
    WG_BARRIER();
    if (kt < 31) {
#pragma unroll
      for (int i = 0; i < 4; ++i) {
        *(u32x4*)((char*)Kl + koff[i]) = rK[i];
        *(u32x4*)((char*)Vl + voff[i]) = rV[i];
      }
    }
    if (kt < 30) {
#pragma unroll
      for (int i = 0; i < 4; ++i) {
        rK[i] = *(const u32x4*)(kgbase + ((size_t)(kt + 2) << 13) + kgo[i]);
        rV[i] = *(const u32x4*)(vgbase + ((size_t)(kt + 2) << 7) + vgo[i]);
      }
    }
    WG_BARRIER();
  }
  // write O(t1)
#pragma unroll
  for (int cd = 0; cd < 4; ++cd)
#pragma unroll
    for (int i = 0; i < 4; ++i) {
      const int q = q0 + 64 + (wid << 4) + (lg << 2) + i;
      const int d = (cd << 4) + lr;
      __builtin_nontemporal_store(oacc[cd][i],
          outO + (((size_t)b * S_LEN + q) << 9) + h * 64 + d);
    }
}

extern "C" void kernel_launch(void* const* d_in, const int* in_sizes, int n_in,
                              void* d_out, int out_size, void* d_ws, size_t ws_size,
                              hipStream_t stream) {
  (void)in_sizes; (void)n_in; (void)out_size; (void)ws_size;
  const float* query = (const float*)d_in[0];
  const float* key_i = (const float*)d_in[1];
  const float* value = (const float*)d_in[2];
  const unsigned char* kpm = (const unsigned char*)d_in[3];
  const float* Wq = (const float*)d_in[4];
  const float* bq_ = (const float*)d_in[5];
  const float* Wk = (const float*)d_in[6];
  const float* bk_ = (const float*)d_in[7];
  const float* Wv = (const float*)d_in[8];
  const float* bv_ = (const float*)d_in[9];

  u16* Qp = (u16*)d_ws;                                  // [16][4096][64] bf16
  u16* Kp = Qp + (size_t)NB * NHD * S_LEN * 64;          // [16][4096][64] bf16
  u16* Vt = Kp + (size_t)NB * NHD * S_LEN * 64;          // [16][64][4096] bf16

  float* outO = (float*)d_out;
  float* outW = outO + (size_t)NB * S_LEN * HID;

  // fused Q/K/V projections: one launch, 768 blocks (3 blocks/CU)
  proj_kernel<<<dim3(64, 4, 3), dim3(256), 0, stream>>>(
      query, key_i, value, Wq, Wk, Wv, bq_, bk_, bv_, Qp, Kp, Vt);
  attn_kernel<<<dim3(512), dim3(256), 0, stream>>>(Qp, Kp, Vt, kpm, outO, outW);
}

// Round 5
// 307.488 us; speedup vs baseline: 3.6686x; 1.4109x over previous
//
#include <hip/hip_runtime.h>

typedef __attribute__((ext_vector_type(4))) float f32x4;
typedef __attribute__((ext_vector_type(8))) short short8;
typedef __attribute__((ext_vector_type(8))) __bf16 bf16x8;
typedef __attribute__((ext_vector_type(4))) unsigned int u32x4;
typedef __attribute__((ext_vector_type(4))) unsigned short u16x4;
typedef unsigned short u16;
typedef unsigned int u32;

#define NB 2
#define S_LEN 4096
#define NHD 8
#define HID 512

__device__ __forceinline__ u16 f2bf(float f) {
  u32 u = __builtin_bit_cast(u32, f);
  u += 0x7fffu + ((u >> 16) & 1u);   // round-to-nearest-even
  return (u16)(u >> 16);
}

// MFMA wrapper hedged over the two plausible builtin signatures (V8s vs V8y).
template <typename V>
static __device__ __forceinline__ auto mfma_imp(V a, V b, f32x4 c, int)
    -> decltype(__builtin_amdgcn_mfma_f32_16x16x32_bf16(a, b, c, 0, 0, 0)) {
  return __builtin_amdgcn_mfma_f32_16x16x32_bf16(a, b, c, 0, 0, 0);
}
template <typename V>
static __device__ __forceinline__ f32x4 mfma_imp(V a, V b, f32x4 c, long) {
  return __builtin_amdgcn_mfma_f32_16x16x32_bf16(
      __builtin_bit_cast(bf16x8, a), __builtin_bit_cast(bf16x8, b), c, 0, 0, 0);
}
static __device__ __forceinline__ f32x4 mfma_bf16(short8 a, short8 b, f32x4 c) {
  return mfma_imp(a, b, c, 0);
}

// Raw workgroup barrier that does NOT drain vmcnt: own LDS ops flushed
// (lgkmcnt 0), scheduler pinned (rule 18), then s_barrier. Global loads and
// the nontemporal W-store stream stay in flight across it.
#define WG_BARRIER()                                        \
  do {                                                      \
    asm volatile("s_waitcnt lgkmcnt(0)" ::: "memory");      \
    __builtin_amdgcn_sched_barrier(0);                      \
    __builtin_amdgcn_s_barrier();                           \
    __builtin_amdgcn_sched_barrier(0);                      \
  } while (0)

// ---------------------------------------------------------------------------
// Fused projection GEMM (Q, K, V in one launch via blockIdx.z):
// C[i][j] = sum_k X[i][k] * W[j][k] + bias[j], scaled, ->bf16
// z==0 (Q): out [(b*8+h)][s][64], scale 0.125 (1/sqrt(64) folded in)
// z==1 (K): out [(b*8+h)][s][64]
// z==2 (V): out [(b*8+h)][64][s]  (V^T so PV B-operand is contiguous)
// ---------------------------------------------------------------------------
__global__ __launch_bounds__(256, 2) void proj_kernel(
    const float* __restrict__ Xq, const float* __restrict__ Xk,
    const float* __restrict__ Xv, const float* __restrict__ Wq,
    const float* __restrict__ Wk, const float* __restrict__ Wv,
    const float* __restrict__ bq_, const float* __restrict__ bk_,
    const float* __restrict__ bv_, u16* __restrict__ oq,
    u16* __restrict__ ok, u16* __restrict__ ov)
{
  __shared__ u16 Al[128 * 64];
  __shared__ u16 Bl[128 * 64];
  const int z = blockIdx.z;
  const float* X = (z == 0) ? Xq : (z == 1) ? Xk : Xv;
  const float* W = (z == 0) ? Wq : (z == 1) ? Wk : Wv;
  const float* bias = (z == 0) ? bq_ : (z == 1) ? bk_ : bv_;
  u16* out = (z == 0) ? oq : (z == 1) ? ok : ov;
  const int transposeOut = (z == 2);
  const float scale = (z == 0) ? 0.125f : 1.0f;

  const int tid = threadIdx.x;
  const int lane = tid & 63;
  const int wid = tid >> 6;
  const int wr = (wid >> 1) << 6;
  const int wc = (wid & 1) << 6;
  const int bm = blockIdx.x << 7;
  const int bn = blockIdx.y << 7;

  f32x4 acc[4][4] = {};

#pragma unroll 1
  for (int k0 = 0; k0 < HID; k0 += 64) {
    __syncthreads();
#pragma unroll
    for (int i = 0; i < 4; ++i) {
      const int idx = i * 256 + tid;
      const int row = idx >> 3;     // 8 chunks of 8 elems per 64-wide row
      const int c = idx & 7;
      const int off = (row * 128 + c * 16) ^ ((row & 7) << 4);
      const float* ga = X + (size_t)(bm + row) * HID + k0 + c * 8;
      f32x4 a0 = *(const f32x4*)ga;
      f32x4 a1 = *(const f32x4*)(ga + 4);
      short8 pa;
      pa[0] = (short)f2bf(a0[0]); pa[1] = (short)f2bf(a0[1]);
      pa[2] = (short)f2bf(a0[2]); pa[3] = (short)f2bf(a0[3]);
      pa[4] = (short)f2bf(a1[0]); pa[5] = (short)f2bf(a1[1]);
      pa[6] = (short)f2bf(a1[2]); pa[7] = (short)f2bf(a1[3]);
      *(short8*)((char*)Al + off) = pa;
      const float* gb = W + (size_t)(bn + row) * HID + k0 + c * 8;
      f32x4 b0 = *(const f32x4*)gb;
      f32x4 b1 = *(const f32x4*)(gb + 4);
      short8 pb;
      pb[0] = (short)f2bf(b0[0]); pb[1] = (short)f2bf(b0[1]);
      pb[2] = (short)f2bf(b0[2]); pb[3] = (short)f2bf(b0[3]);
      pb[4] = (short)f2bf(b1[0]); pb[5] = (short)f2bf(b1[1]);
      pb[6] = (short)f2bf(b1[2]); pb[7] = (short)f2bf(b1[3]);
      *(short8*)((char*)Bl + off) = pb;
    }
    __syncthreads();
#pragma unroll
    for (int ks = 0; ks < 2; ++ks) {
      const int koffb = (ks * 32 + ((lane >> 4) << 3)) * 2;
      short8 af[4], bfr[4];
#pragma unroll
      for (int m = 0; m < 4; ++m) {
        const int row = wr + m * 16 + (lane & 15);
        af[m] = *(const short8*)((const char*)Al + ((row * 128 + koffb) ^ ((row & 7) << 4)));
      }
#pragma unroll
      for (int n = 0; n < 4; ++n) {
        const int row = wc + n * 16 + (lane & 15);
        bfr[n] = *(const short8*)((const char*)Bl + ((row * 128 + koffb) ^ ((row & 7) << 4)));
      }
#pragma unroll
      for (int m = 0; m < 4; ++m)
#pragma unroll
        for (int n = 0; n < 4; ++n)
          acc[m][n] = mfma_bf16(af[m], bfr[n], acc[m][n]);
    }
  }

#pragma unroll
  for (int n = 0; n < 4; ++n) {
    const int j = bn + wc + n * 16 + (lane & 15);
    const float bj = bias[j];
    const int h = j >> 6, d = j & 63;
#pragma unroll
    for (int m = 0; m < 4; ++m) {
      const int rbase = bm + wr + m * 16 + ((lane >> 4) << 2);
      const int b = rbase >> 12;
      const int s = rbase & (S_LEN - 1);
      if (!transposeOut) {
#pragma unroll
        for (int i = 0; i < 4; ++i) {
          const float v = (acc[m][n][i] + bj) * scale;
          out[(((size_t)(b * NHD + h) * S_LEN + (s + i)) << 6) + d] = f2bf(v);
        }
      } else {
        u16x4 pk;
#pragma unroll
        for (int i = 0; i < 4; ++i) pk[i] = f2bf((acc[m][n][i] + bj) * scale);
        *(u16x4*)(out + (((size_t)(b * NHD + h) * 64 + d) << 12) + s) = pk;
      }
    }
  }
}

// ---------------------------------------------------------------------------
// Fused attention, q-tile-pair pipelined + LDS-transposed W stores.
// One WG per (b*8+h, 128 q-rows) = two 64-row tiles t0,t1; 4 waves x 16
// q-rows per tile. Phases: A0 (denominators t0), phase1 (B t0 + A t1),
// phase2 (B t1) — round-2 pipelined staging, non-draining barriers.
// Round-4 change: normalized fp32 P goes to a per-wave LDS buffer Wl
// (swizzled), then is read back ROW-MAJOR and nt-stored as 8x 1-KB
// instructions covering contiguous 512-B row segments (vs 64-B scatter
// before) — HBM write efficiency. PV reads fp32 from Wl and converts to
// bf16 in-register (conversion moved, not added; Pl buffer deleted).
// ---------------------------------------------------------------------------
__global__ __launch_bounds__(256, 2) void attn_kernel(
    const u16* __restrict__ Qp, const u16* __restrict__ Kp,
    const u16* __restrict__ Vt, const unsigned char* __restrict__ mask,
    float* __restrict__ outO, float* __restrict__ outW)
{
  __shared__ u16 Kl[128 * 64];        // K tile (16 KB)
  __shared__ u16 Vl[64 * 128];        // V^T tile (16 KB)
  __shared__ float Wl[4][16 * 128];   // per-wave fp32 normalized P (32 KB)
  __shared__ u32 anyMaskSh;

  const int tid = threadIdx.x;
  const int lane = tid & 63;
  const int wid = tid >> 6;
  const int lr = lane & 15;
  const int lg = lane >> 4;

  // XCD-bijective swizzle: 512 blocks; each XCD gets a 64-block chunk = 2
  // heads (K+V+Q = 3 MB fits the 4 MB per-XCD L2).
  const int bid = blockIdx.x;
  const int swz = (bid & 7) * 64 + (bid >> 3);
  const int bh = swz >> 5;          // b*8 + h
  const int q0 = (swz & 31) << 7;   // 128 q-rows = tiles t0,t1
  const int b = bh >> 3;
  const int h = bh & 7;

  char* const Wlw = (char*)Wl[wid];

  // per-thread staging offsets (K tile: [128][64]; V tile: [64][128] keys)
  int koff[4], kgo[4], voff[4], vgo[4];
#pragma unroll
  for (int i = 0; i < 4; ++i) {
    const int idx = i * 256 + tid;
    const int kr = idx >> 3, kc = idx & 7;
    koff[i] = (kr * 128 + kc * 16) ^ ((kr & 7) << 4);
    kgo[i] = (kr << 6) + kc * 8;
    const int vr = idx >> 4, vc = idx & 15;
    voff[i] = (vr * 256 + vc * 16) ^ ((vr & 7) << 4);
    vgo[i] = (vr << 12) + vc * 8;
  }
  const u16* kgbase = Kp + ((size_t)bh << 18);
  const u16* vgbase = Vt + ((size_t)bh << 18);

  if (tid == 0) anyMaskSh = 0u;
  __syncthreads();
  {
    u32x4 mv = *(const u32x4*)(mask + (size_t)b * S_LEN + tid * 16);
    if (mv[0] | mv[1] | mv[2] | mv[3]) atomicOr(&anyMaskSh, 1u);
  }
  __syncthreads();
  const bool anyMask = (anyMaskSh != 0u);

  // Q fragments (MFMA B operand) for both tiles, straight from global (one-time)
  short8 bq[2][2];
#pragma unroll
  for (int t = 0; t < 2; ++t)
#pragma unroll
    for (int ks = 0; ks < 2; ++ks) {
      const int qr = q0 + (t << 6) + (wid << 4) + lr;
      bq[t][ks] = *(const short8*)(
          Qp + (((size_t)bh * S_LEN + qr) << 6) + ks * 32 + lg * 8);
    }

  const unsigned char* mrow = mask + (size_t)b * S_LEN + (lg << 2);
  u32x4 rK[4], rV[4];

  // ---------------- phase A0: denominators for t0 ----------------
#pragma unroll
  for (int i = 0; i < 4; ++i) rK[i] = *(const u32x4*)(kgbase + kgo[i]);
#pragma unroll
  for (int i = 0; i < 4; ++i) *(u32x4*)((char*)Kl + koff[i]) = rK[i];
#pragma unroll
  for (int i = 0; i < 4; ++i) rK[i] = *(const u32x4*)(kgbase + (1 << 13) + kgo[i]);
  WG_BARRIER();

  float lsum0 = 0.f;
#pragma unroll 1
  for (int kt = 0; kt < 32; ++kt) {
#pragma unroll
    for (int rb = 0; rb < 8; ++rb) {
      const int krow = (rb << 4) + lr;
      short8 ak0 = *(const short8*)((const char*)Kl +
          ((krow * 128 + (lg << 4)) ^ ((krow & 7) << 4)));
      short8 ak1 = *(const short8*)((const char*)Kl +
          ((krow * 128 + 64 + (lg << 4)) ^ ((krow & 7) << 4)));
      u32 mw = 0u;
      if (anyMask) mw = *(const u32*)(mrow + (kt << 7) + (rb << 4));
      f32x4 sv = {};
      sv = mfma_bf16(ak0, bq[0][0], sv);
      sv = mfma_bf16(ak1, bq[0][1], sv);
      float p0 = __expf(sv[0]);
      float p1 = __expf(sv[1]);
      float p2 = __expf(sv[2]);
      float p3 = __expf(sv[3]);
      if (mw) {
        if (mw & 0x000000FFu) p0 = 0.f;
        if (mw & 0x0000FF00u) p1 = 0.f;
        if (mw & 0x00FF0000u) p2 = 0.f;
        if (mw & 0xFF000000u) p3 = 0.f;
      }
      lsum0 += (p0 + p1) + (p2 + p3);
    }
    WG_BARRIER();
    if (kt < 31) {
#pragma unroll
      for (int i = 0; i < 4; ++i) *(u32x4*)((char*)Kl + koff[i]) = rK[i];
    }
    if (kt < 30) {
#pragma unroll
      for (int i = 0; i < 4; ++i)
        rK[i] = *(const u32x4*)(kgbase + ((size_t)(kt + 2) << 13) + kgo[i]);
    }
    WG_BARRIER();
  }
  float inv0;
  {
    float t = lsum0;
    t += __shfl_xor(t, 16);
    t += __shfl_xor(t, 32);
    inv0 = 1.0f / t;
  }

  // ---------------- phase 1: B(t0) + A(t1) ----------------
#pragma unroll
  for (int i = 0; i < 4; ++i) {
    rK[i] = *(const u32x4*)(kgbase + kgo[i]);
    rV[i] = *(const u32x4*)(vgbase + vgo[i]);
  }
#pragma unroll
  for (int i = 0; i < 4; ++i) {
    *(u32x4*)((char*)Kl + koff[i]) = rK[i];
    *(u32x4*)((char*)Vl + voff[i]) = rV[i];
  }
#pragma unroll
  for (int i = 0; i < 4; ++i) {
    rK[i] = *(const u32x4*)(kgbase + (1 << 13) + kgo[i]);
    rV[i] = *(const u32x4*)(vgbase + (1 << 7) + vgo[i]);
  }
  WG_BARRIER();

  float lsum1 = 0.f;
  f32x4 oacc[4] = {};
  float* const wb0 = outW + ((size_t)(bh * S_LEN + q0 + (wid << 4)) << 12);
#pragma unroll 1
  for (int kt = 0; kt < 32; ++kt) {
#pragma unroll
    for (int rb = 0; rb < 8; ++rb) {
      const int krow = (rb << 4) + lr;
      short8 ak0 = *(const short8*)((const char*)Kl +
          ((krow * 128 + (lg << 4)) ^ ((krow & 7) << 4)));
      short8 ak1 = *(const short8*)((const char*)Kl +
          ((krow * 128 + 64 + (lg << 4)) ^ ((krow & 7) << 4)));
      u32 mw = 0u;
      if (anyMask) mw = *(const u32*)(mrow + (kt << 7) + (rb << 4));
      // B for t0: normalized fp32 P -> Wl (swizzled)
      {
        f32x4 sv = {};
        sv = mfma_bf16(ak0, bq[0][0], sv);
        sv = mfma_bf16(ak1, bq[0][1], sv);
        float p0 = __expf(sv[0]) * inv0;
        float p1 = __expf(sv[1]) * inv0;
        float p2 = __expf(sv[2]) * inv0;
        float p3 = __expf(sv[3]) * inv0;
        if (mw) {
          if (mw & 0x000000FFu) p0 = 0.f;
          if (mw & 0x0000FF00u) p1 = 0.f;
          if (mw & 0x00FF0000u) p2 = 0.f;
          if (mw & 0xFF000000u) p3 = 0.f;
        }
        f32x4 wv; wv[0] = p0; wv[1] = p1; wv[2] = p2; wv[3] = p3;
        *(f32x4*)(Wlw + (((lr << 9) + (rb << 6) + (lg << 4)) ^ ((lr & 7) << 4))) = wv;
      }
      // A for t1 (same ak fragments — K rows are q-independent)
      {
        f32x4 sv = {};
        sv = mfma_bf16(ak0, bq[1][0], sv);
        sv = mfma_bf16(ak1, bq[1][1], sv);
        float p0 = __expf(sv[0]);
        float p1 = __expf(sv[1]);
        float p2 = __expf(sv[2]);
        float p3 = __expf(sv[3]);
        if (mw) {
          if (mw & 0x000000FFu) p0 = 0.f;
          if (mw & 0x0000FF00u) p1 = 0.f;
          if (mw & 0x00FF0000u) p2 = 0.f;
          if (mw & 0xFF000000u) p3 = 0.f;
        }
        lsum1 += (p0 + p1) + (p2 + p3);
      }
    }
    // store-out: read Wl row-major, 8x 1-KB nt stores (2x contiguous 512 B)
#pragma unroll
    for (int i = 0; i < 8; ++i) {
      const int row = (i << 1) + (lane >> 5);
      f32x4 wv = *(const f32x4*)(Wlw +
          (((row << 9) + ((lane & 31) << 4)) ^ ((row & 7) << 4)));
      __builtin_nontemporal_store(wv,
          (f32x4*)(wb0 + ((size_t)row << 12) + (kt << 7) + ((lane & 31) << 2)));
    }
    // PV for t0: read fp32 P from Wl (same-wave RAW), convert to bf16
#pragma unroll
    for (int kk = 0; kk < 4; ++kk) {
      const int wbo = (lr << 9) + (kk << 7) + (lg << 5);
      f32x4 a0 = *(const f32x4*)(Wlw + (wbo ^ ((lr & 7) << 4)));
      f32x4 a1 = *(const f32x4*)(Wlw + ((wbo + 16) ^ ((lr & 7) << 4)));
      short8 ap;
      ap[0] = (short)f2bf(a0[0]); ap[1] = (short)f2bf(a0[1]);
      ap[2] = (short)f2bf(a0[2]); ap[3] = (short)f2bf(a0[3]);
      ap[4] = (short)f2bf(a1[0]); ap[5] = (short)f2bf(a1[1]);
      ap[6] = (short)f2bf(a1[2]); ap[7] = (short)f2bf(a1[3]);
#pragma unroll
      for (int cd = 0; cd < 4; ++cd) {
        const int drow = (cd << 4) + lr;
        short8 bv = *(const short8*)((const char*)Vl +
            ((drow * 256 + (kk << 6) + (lg << 4)) ^ ((drow & 7) << 4)));
        oacc[cd] = mfma_bf16(ap, bv, oacc[cd]);
      }
    }
    WG_BARRIER();
    if (kt < 31) {
#pragma unroll
      for (int i = 0; i < 4; ++i) {
        *(u32x4*)((char*)Kl + koff[i]) = rK[i];
        *(u32x4*)((char*)Vl + voff[i]) = rV[i];
      }
    }
    if (kt < 30) {
#pragma unroll
      for (int i = 0; i < 4; ++i) {
        rK[i] = *(const u32x4*)(kgbase + ((size_t)(kt + 2) << 13) + kgo[i]);
        rV[i] = *(const u32x4*)(vgbase + ((size_t)(kt + 2) << 7) + vgo[i]);
      }
    }
    WG_BARRIER();
  }
  float inv1;
  {
    float t = lsum1;
    t += __shfl_xor(t, 16);
    t += __shfl_xor(t, 32);
    inv1 = 1.0f / t;
  }
  // write O(t0); free oacc for t1
#pragma unroll
  for (int cd = 0; cd < 4; ++cd)
#pragma unroll
    for (int i = 0; i < 4; ++i) {
      const int q = q0 + (wid << 4) + (lg << 2) + i;
      const int d = (cd << 4) + lr;
      __builtin_nontemporal_store(oacc[cd][i],
          outO + (((size_t)b * S_LEN + q) << 9) + h * 64 + d);
      oacc[cd][i] = 0.f;
    }

  // ---------------- phase 2: B(t1) ----------------
#pragma unroll
  for (int i = 0; i < 4; ++i) {
    rK[i] = *(const u32x4*)(kgbase + kgo[i]);
    rV[i] = *(const u32x4*)(vgbase + vgo[i]);
  }
#pragma unroll
  for (int i = 0; i < 4; ++i) {
    *(u32x4*)((char*)Kl + koff[i]) = rK[i];
    *(u32x4*)((char*)Vl + voff[i]) = rV[i];
  }
#pragma unroll
  for (int i = 0; i < 4; ++i) {
    rK[i] = *(const u32x4*)(kgbase + (1 << 13) + kgo[i]);
    rV[i] = *(const u32x4*)(vgbase + (1 << 7) + vgo[i]);
  }
  WG_BARRIER();

  float* const wb1 = outW + ((size_t)(bh * S_LEN + q0 + 64 + (wid << 4)) << 12);
#pragma unroll 1
  for (int kt = 0; kt < 32; ++kt) {
#pragma unroll
    for (int rb = 0; rb < 8; ++rb) {
      const int krow = (rb << 4) + lr;
      short8 ak0 = *(const short8*)((const char*)Kl +
          ((krow * 128 + (lg << 4)) ^ ((krow & 7) << 4)));
      short8 ak1 = *(const short8*)((const char*)Kl +
          ((krow * 128 + 64 + (lg << 4)) ^ ((krow & 7) << 4)));
      u32 mw = 0u;
      if (anyMask) mw = *(const u32*)(mrow + (kt << 7) + (rb << 4));
      f32x4 sv = {};
      sv = mfma_bf16(ak0, bq[1][0], sv);
      sv = mfma_bf16(ak1, bq[1][1], sv);
      float p0 = __expf(sv[0]) * inv1;
      float p1 = __expf(sv[1]) * inv1;
      float p2 = __expf(sv[2]) * inv1;
      float p3 = __expf(sv[3]) * inv1;
      if (mw) {
        if (mw & 0x000000FFu) p0 = 0.f;
        if (mw & 0x0000FF00u) p1 = 0.f;
        if (mw & 0x00FF0000u) p2 = 0.f;
        if (mw & 0xFF000000u) p3 = 0.f;
      }
      f32x4 wv; wv[0] = p0; wv[1] = p1; wv[2] = p2; wv[3] = p3;
      *(f32x4*)(Wlw + (((lr << 9) + (rb << 6) + (lg << 4)) ^ ((lr & 7) << 4))) = wv;
    }
#pragma unroll
    for (int i = 0; i < 8; ++i) {
      const int row = (i << 1) + (lane >> 5);
      f32x4 wv = *(const f32x4*)(Wlw +
          (((row << 9) + ((lane & 31) << 4)) ^ ((row & 7) << 4)));
      __builtin_nontemporal_store(wv,
          (f32x4*)(wb1 + ((size_t)row << 12) + (kt << 7) + ((lane & 31) << 2)));
    }
#pragma unroll
    for (int kk = 0; kk < 4; ++kk) {
      const int wbo = (lr << 9) + (kk << 7) + (lg << 5);
      f32x4 a0 = *(const f32x4*)(Wlw + (wbo ^ ((lr & 7) << 4)));
      f32x4 a1 = *(const f32x4*)(Wlw + ((wbo + 16) ^ ((lr & 7) << 4)));
      short8 ap;
      ap[0] = (short)f2bf(a0[0]); ap[1] = (short)f2bf(a0[1]);
      ap[2] = (short)f2bf(a0[2]); ap[3] = (short)f2bf(a0[3]);
      ap[4] = (short)f2bf(a1[0]); ap[5] = (short)f2bf(a1[1]);
      ap[6] = (short)f2bf(a1[2]); ap[7] = (short)f2bf(a1[3]);
#pragma unroll
      for (int cd = 0; cd < 4; ++cd) {
        const int drow = (cd << 4) + lr;
        short8 bv = *(const short8*)((const char*)Vl +
            ((drow * 256 + (kk << 6) + (lg << 4)) ^ ((drow & 7) << 4)));
        oacc[cd] = mfma_bf16(ap, bv, oacc[cd]);
      }
    }
    WG_BARRIER();
    if (kt < 31) {
#pragma unroll
      for (int i = 0; i < 4; ++i) {
        *(u32x4*)((char*)Kl + koff[i]) = rK[i];
        *(u32x4*)((char*)Vl + voff[i]) = rV[i];
      }
    }
    if (kt < 30) {
#pragma unroll
      for (int i = 0; i < 4; ++i) {
        rK[i] = *(const u32x4*)(kgbase + ((size_t)(kt + 2) << 13) + kgo[i]);
        rV[i] = *(const u32x4*)(vgbase + ((size_t)(kt + 2) << 7) + vgo[i]);
      }
    }
    WG_BARRIER();
  }
  // write O(t1)
#pragma unroll
  for (int cd = 0; cd < 4; ++cd)
#pragma unroll
    for (int i = 0; i < 4; ++i) {
      const int q = q0 + 64 + (wid << 4) + (lg << 2) + i;
      const int d = (cd << 4) + lr;
      __builtin_nontemporal_store(oacc[cd][i],
          outO + (((size_t)b * S_LEN + q) << 9) + h * 64 + d);
    }
}

extern "C" void kernel_launch(void* const* d_in, const int* in_sizes, int n_in,
                              void* d_out, int out_size, void* d_ws, size_t ws_size,
                              hipStream_t stream) {
  (void)in_sizes; (void)n_in; (void)out_size; (void)ws_size;
  const float* query = (const float*)d_in[0];
  const float* key_i = (const float*)d_in[1];
  const float* value = (const float*)d_in[2];
  const unsigned char* kpm = (const unsigned char*)d_in[3];
  const float* Wq = (const float*)d_in[4];
  const float* bq_ = (const float*)d_in[5];
  const float* Wk = (const float*)d_in[6];
  const float* bk_ = (const float*)d_in[7];
  const float* Wv = (const float*)d_in[8];
  const float* bv_ = (const float*)d_in[9];

  u16* Qp = (u16*)d_ws;                                  // [16][4096][64] bf16
  u16* Kp = Qp + (size_t)NB * NHD * S_LEN * 64;          // [16][4096][64] bf16
  u16* Vt = Kp + (size_t)NB * NHD * S_LEN * 64;          // [16][64][4096] bf16

  float* outO = (float*)d_out;
  float* outW = outO + (size_t)NB * S_LEN * HID;

  // fused Q/K/V projections: one launch, 768 blocks (3 blocks/CU)
  proj_kernel<<<dim3(64, 4, 3), dim3(256), 0, stream>>>(
      query, key_i, value, Wq, Wk, Wv, bq_, bk_, bv_, Qp, Kp, Vt);
  attn_kernel<<<dim3(512), dim3(256), 0, stream>>>(Qp, Kp, Vt, kpm, outO, outW);
}